// Round 1
// baseline (460.315 us; speedup 1.0000x reference)
//
#include <hip/hip_runtime.h>
#include <stdint.h>

#define H8 64
#define W8 64
#define NB 4
#define NC 256
#define TC 5440   // cells per batch across all 4 levels: 4096+1024+256+64

typedef short bf16x8 __attribute__((ext_vector_type(8)));
typedef float f32x4  __attribute__((ext_vector_type(4)));

__device__ __forceinline__ unsigned short f2b(float x){
  uint32_t u = __float_as_uint(x);
  uint32_t r = (u + 0x7FFFu + ((u >> 16) & 1u)) >> 16;   // RNE to bf16
  return (unsigned short)r;
}
__device__ __forceinline__ float b2f(unsigned short u){
  return __uint_as_float(((uint32_t)u) << 16);
}

// Transpose [b][c][p] fp32 -> [b][p][c] bf16 for f1 (z<4) and f2 level-0 (z>=4).
__global__ void transpose_cvt(const float* __restrict__ f1, const float* __restrict__ f2,
                              unsigned short* __restrict__ f1t, unsigned short* __restrict__ f2p){
  __shared__ float tile[32][33];
  const int z = blockIdx.z; const int bb = z & 3;
  const float* src = (z < 4) ? f1 : f2;
  const int p0 = blockIdx.x * 32, c0 = blockIdx.y * 32;
  const int tx = threadIdx.x, ty = threadIdx.y;   // block (32,8)
  #pragma unroll
  for (int r = 0; r < 4; ++r){
    int c = c0 + ty + r*8;
    tile[ty + r*8][tx] = src[((size_t)bb*NC + c)*4096 + p0 + tx];
  }
  __syncthreads();
  unsigned short* dst = (z < 4) ? f1t : f2p;
  #pragma unroll
  for (int r = 0; r < 4; ++r){
    int p = p0 + ty + r*8;
    size_t o = (z < 4) ? ((size_t)(bb*4096 + p))*NC : ((size_t)(bb*TC + p))*NC;
    dst[o + c0 + tx] = f2b(tile[tx][ty + r*8]);
  }
}

// 2x2 average-pool of cell-major bf16 feature maps (pool commutes with the dot).
__global__ void pool_lvl(unsigned short* __restrict__ f2p, int in_off, int out_off,
                         int lwk, int lcells){
  int idx  = blockIdx.x * 256 + threadIdx.x;
  int c    = idx & 255;
  int rest = idx >> 8;
  int cell = rest & ((1 << lcells) - 1);
  int bb   = rest >> lcells;
  int wk   = 1 << lwk;
  int u = cell >> lwk, v = cell & (wk - 1);
  int win = wk << 1;
  const unsigned short* base = f2p + ((size_t)bb*TC + in_off)*NC + c;
  int i00 = (2*u)*win + 2*v;
  float s = b2f(base[(size_t)i00*NC])        + b2f(base[(size_t)(i00+1)*NC])
          + b2f(base[(size_t)(i00+win)*NC])  + b2f(base[(size_t)(i00+win+1)*NC]);
  f2p[((size_t)(bb*TC + out_off) + cell)*NC + c] = f2b(0.25f * s);
}

// One wave per query pixel. Per level: MFMA-compute a 10x10 corr box (M=16 cells
// per pass, B = f1 column broadcast -> C col 0), then 41 bilinear taps from LDS.
__global__ __launch_bounds__(256) void lookup_main(const float* __restrict__ flow,
                 const unsigned short* __restrict__ f1t,
                 const unsigned short* __restrict__ f2p,
                 float* __restrict__ out){
  const int lane = threadIdx.x & 63;
  const int wid  = threadIdx.x >> 6;
  // XCD swizzle: blockIdx%8 -> batch pair, keeps one batch's pooled f2 per XCD L2
  const int Bk = blockIdx.x;
  const int xs = Bk & 7;
  const int bb = xs >> 1;
  const int sub = ((Bk >> 3) << 1) | (xs & 1);   // 0..1023 within batch
  const int pix = (sub << 2) | wid;              // 0..4095
  const int i = pix >> 6, j = pix & 63;

  __shared__ __align__(16) unsigned short f1s[4][NC];
  __shared__ float box[4][112];

  {
    const unsigned short* f1c = f1t + ((size_t)(bb*4096 + pix))*NC;
    ((uint2*)&f1s[wid][0])[lane] = ((const uint2*)f1c)[lane];  // 512B column
  }
  const float fy = flow[((bb*2 + 0)*H8 + i)*W8 + j];
  const float fx = flow[((bb*2 + 1)*H8 + i)*W8 + j];
  asm volatile("s_waitcnt lgkmcnt(0)" ::: "memory");

  // diamond offset (dy,dx) for tap t = lane (lane < 41), reference enumeration order
  int dy = 0, dx = 0;
  {
    int rem = lane;
    #pragma unroll
    for (int ry = -4; ry <= 4; ++ry){
      int ab = ry < 0 ? -ry : ry;
      int ln = 9 - 2*ab;
      if (rem >= 0 && rem < ln){ dy = ry; dx = rem + (ab - 4); }
      rem -= ln;
    }
  }

  const int g    = lane >> 4;    // k-chunk group 0..3
  const int mrow = lane & 15;    // A-row = cell within pass
  const int LVO[4] = {0, 4096, 5120, 5376};
  float inv = 1.0f;

  #pragma unroll
  for (int k = 0; k < 4; ++k){
    const int h = H8 >> k;
    const float s = (float)(h - 1) / (float)h;
    const float yc = ((float)i + fy) * inv;
    const float xc = ((float)j + fx) * inv;
    const int y0b = (int)floorf((yc - 4.0f) * s);
    const int x0b = (int)floorf((xc - 4.0f) * s);
    const unsigned short* lv = f2p + ((size_t)bb*TC + LVO[k])*NC;

    for (int p = 0; p < 7; ++p){
      const int cp = p*16 + mrow;           // cell 0..111 in 10x10(+pad) box
      const int ca = cp / 10;
      const int cb = cp - ca*10;
      const int gy = y0b + ca, gx = x0b + cb;
      const int gyc = min(max(gy, 0), h-1);
      const int gxc = min(max(gx, 0), h-1);
      const unsigned short* col = lv + (size_t)(gyc*h + gxc)*NC;
      f32x4 acc = {0.f, 0.f, 0.f, 0.f};
      #pragma unroll
      for (int st = 0; st < 8; ++st){
        const int ch = st*32 + g*8;
        bf16x8 av = *(const bf16x8*)(col + ch);          // A[m=cell][k]
        bf16x8 bv = *(const bf16x8*)(&f1s[wid][ch]);     // B[k][n] broadcast over n
        acc = __builtin_amdgcn_mfma_f32_16x16x32_bf16(av, bv, acc, 0, 0, 0);
      }
      // C/D: col = lane&15 (we want n=0), row = (lane>>4)*4 + reg  [m89-verified]
      if (mrow == 0){
        #pragma unroll
        for (int r = 0; r < 4; ++r){
          int cq  = p*16 + g*4 + r;
          int ca2 = cq / 10, cb2 = cq - ca2*10;
          int gy2 = y0b + ca2, gx2 = x0b + cb2;
          bool val = (cq < 100) & (gy2 >= 0) & (gy2 < h) & (gx2 >= 0) & (gx2 < h);
          box[wid][cq] = val ? acc[r] * 0.0625f : 0.0f;  // /sqrt(C)=16
        }
      }
    }
    asm volatile("s_waitcnt lgkmcnt(0)" ::: "memory");
    if (lane < 41){
      float py = (yc + (float)dy) * s;
      float px = (xc + (float)dx) * s;
      float fy0 = floorf(py), fx0 = floorf(px);
      float wy1 = py - fy0, wx1 = px - fx0;
      float wy0 = 1.0f - wy1, wx0 = 1.0f - wx1;
      int iy = (int)fy0 - y0b;
      int ix = (int)fx0 - x0b;
      const float* bx = &box[wid][iy*10 + ix];
      float v = wy0*(wx0*bx[0] + wx1*bx[1]) + wy1*(wx0*bx[10] + wx1*bx[11]);
      out[((size_t)(bb*4096 + pix)*4 + k)*41 + lane] = v;
    }
    asm volatile("s_waitcnt lgkmcnt(0)" ::: "memory");
    inv *= 0.5f;
  }
}

extern "C" void kernel_launch(void* const* d_in, const int* in_sizes, int n_in,
                              void* d_out, int out_size, void* d_ws, size_t ws_size,
                              hipStream_t stream){
  const float* feat1 = (const float*)d_in[0];
  const float* feat2 = (const float*)d_in[1];
  const float* flow  = (const float*)d_in[2];
  float* out = (float*)d_out;
  unsigned short* f1t = (unsigned short*)d_ws;                 // 4*4096*256 bf16 = 8.4 MB
  unsigned short* f2p = f1t + (size_t)NB*4096*NC;              // 4*5440*256 bf16 = 11.1 MB

  transpose_cvt<<<dim3(128, 8, 8), dim3(32, 8, 1), 0, stream>>>(feat1, feat2, f1t, f2p);
  pool_lvl<<<(NB*1024*NC)/256, 256, 0, stream>>>(f2p,    0, 4096, 5, 10);
  pool_lvl<<<(NB* 256*NC)/256, 256, 0, stream>>>(f2p, 4096, 5120, 4,  8);
  pool_lvl<<<(NB*  64*NC)/256, 256, 0, stream>>>(f2p, 5120, 5376, 3,  6);
  lookup_main<<<4096, 256, 0, stream>>>(flow, f1t, f2p, out);
}